// Round 15
// baseline (110.277 us; speedup 1.0000x reference)
//
#include <hip/hip_runtime.h>

#define NNODES 50000
#define NEDGES 800000
#define CAP 64                         // bucket capacity per node (max deg ~45 for Poisson(16))
#define PFINE 256                      // nodes per fine partition
#define NPF ((NNODES + PFINE - 1) / PFINE)   // 196
#define CAPPF 8192                     // binned capacity per partition
#define EPB 1024                       // edges per bin block
#define NBINBLK ((NEDGES + EPB - 1) / EPB)   // 782

typedef _Float16 half2v __attribute__((ext_vector_type(2)));
typedef _Float16 half4v __attribute__((ext_vector_type(4)));
typedef _Float16 half8v __attribute__((ext_vector_type(8)));
typedef float floatx4 __attribute__((ext_vector_type(4)));
typedef unsigned short ushort4v __attribute__((ext_vector_type(4)));
typedef unsigned short ushort8v __attribute__((ext_vector_type(8)));

__global__ void zero_pcnt(int* __restrict__ p) {
    if (threadIdx.x < NPF) p[threadIdx.x] = 0;
}

// Phase A: bin edges by fine partition (d>>8). Packed: (src<<8) | (d&255).
__global__ __launch_bounds__(256) void bin_kernel(
        const int* __restrict__ src, const int* __restrict__ dst,
        int* __restrict__ pcnt, unsigned int* __restrict__ binned) {
    __shared__ int lcnt[NPF];
    __shared__ int gbase[NPF];
    const int tid = threadIdx.x;
    for (int i = tid; i < NPF; i += 256) lcnt[i] = 0;
    __syncthreads();
    const int e0 = blockIdx.x * EPB;
    int myp[4], myrank[4];
    unsigned int myval[4];
#pragma unroll
    for (int k = 0; k < 4; ++k) {
        int e = e0 + k * 256 + tid;
        if (e < NEDGES) {
            int d = dst[e], s = src[e];
            int p = d >> 8;
            myp[k] = p;
            myrank[k] = atomicAdd(&lcnt[p], 1);
            myval[k] = ((unsigned int)s << 8) | (unsigned int)(d & 255);
        } else myp[k] = -1;
    }
    __syncthreads();
    for (int p = tid; p < NPF; p += 256) gbase[p] = atomicAdd(&pcnt[p], lcnt[p]);
    __syncthreads();
#pragma unroll
    for (int k = 0; k < 4; ++k) {
        if (myp[k] >= 0) {
            int idx = gbase[myp[k]] + myrank[k];
            if (idx < CAPPF) binned[(size_t)myp[k] * CAPPF + idx] = myval[k];
        }
    }
}

// Phase B: build one partition's bucket region in LDS (LDS atomics), stream out
// full lines, write dinv, and emit a degree-sorted permutation
// perm[nodebase+rank] = nid | (clamped_deg << 16)  (counting sort, 65 bins).
__global__ __launch_bounds__(512) void fillB_kernel(
        const unsigned int* __restrict__ binned, const int* __restrict__ pcnt,
        float* __restrict__ dinv, unsigned int* __restrict__ perm,
        unsigned short* __restrict__ bucket) {
    __shared__ __align__(16) unsigned short lbuck[PFINE * CAP];  // 32 KB
    __shared__ int lcnt[PFINE];                                  // 1 KB
    __shared__ int hist[CAP + 1];
    const int tid = threadIdx.x;
    const int p = blockIdx.x;
    for (int i = tid; i < PFINE; i += 512) lcnt[i] = 0;
    if (tid <= CAP) hist[tid] = 0;
    __syncthreads();
    int n = pcnt[p]; if (n > CAPPF) n = CAPPF;
    const unsigned int* bp = binned + (size_t)p * CAPPF;
    for (int i = tid; i < n; i += 512) {
        unsigned int v = bp[i];
        int dl = (int)(v & 255u);
        int pos = atomicAdd(&lcnt[dl], 1);
        if (pos < CAP) lbuck[dl * CAP + pos] = (unsigned short)(v >> 8);
    }
    __syncthreads();
    const int nodebase = p * PFINE;
    int nn = NNODES - nodebase; if (nn > PFINE) nn = PFINE;
    // bucket writeout (coalesced full lines)
    int4* gb = (int4*)(bucket + (size_t)nodebase * CAP);
    const int4* lb = (const int4*)lbuck;
    const int tot4 = nn * (CAP / 8);
    for (int i = tid; i < tot4; i += 512) gb[i] = lb[i];
    // dinv + degree histogram
    for (int i = tid; i < nn; i += 512) {
        int c = lcnt[i];
        dinv[nodebase + i] = 1.0f / sqrtf((float)c + 1.0f);
        int cc = c > CAP ? CAP : c;
        atomicAdd(&hist[cc], 1);
    }
    __syncthreads();
    if (tid == 0) {                      // exclusive scan, 65 entries
        int s = 0;
        for (int d = 0; d <= CAP; ++d) { int h = hist[d]; hist[d] = s; s += h; }
    }
    __syncthreads();
    for (int i = tid; i < nn; i += 512) {
        int c = lcnt[i];
        int cc = c > CAP ? CAP : c;
        int r = atomicAdd(&hist[cc], 1);
        perm[nodebase + r] = (unsigned int)(nodebase + i) | ((unsigned int)cc << 16);
    }
}

// h1w[r,:] = dinv[r] * (X[r,:] @ W1)  via fp16 MFMA, fp16 output.
__global__ __launch_bounds__(256) void gemm1_mfma(
    const float* __restrict__ X, const float* __restrict__ W,
    const float* __restrict__ dinv, _Float16* __restrict__ H, int N)
{
    __shared__ _Float16 outs[64][136];
    const int tid  = threadIdx.x;
    const int lane = tid & 63;
    const int wv   = tid >> 6;
    const int mh   = wv >> 1;
    const int nh   = wv & 1;
    const int t    = lane & 15;
    const int g    = lane >> 4;
    const int row0 = blockIdx.x * 64;

    half8v bf[4][4];
#pragma unroll
    for (int s = 0; s < 4; ++s) {
#pragma unroll
        for (int nt = 0; nt < 4; ++nt) {
            const float* wp = W + (size_t)(s * 32 + g * 8) * 128 + nh * 64 + nt * 16 + t;
            half8v h;
#pragma unroll
            for (int i = 0; i < 8; ++i) h[i] = (_Float16)wp[(size_t)i * 128];
            bf[s][nt] = h;
        }
    }

    floatx4 acc[2][4];
#pragma unroll
    for (int mt = 0; mt < 2; ++mt)
#pragma unroll
        for (int nt = 0; nt < 4; ++nt) acc[mt][nt] = (floatx4){0.f, 0.f, 0.f, 0.f};

#pragma unroll
    for (int s = 0; s < 4; ++s) {
#pragma unroll
        for (int mt = 0; mt < 2; ++mt) {
            int r = row0 + mh * 32 + mt * 16 + t;
            if (r > N - 1) r = N - 1;
            const float* xp = X + (size_t)r * 128 + s * 32 + g * 8;
            float4 x0 = *(const float4*)xp;
            float4 x1 = *(const float4*)(xp + 4);
            half8v af;
            af[0] = (_Float16)x0.x; af[1] = (_Float16)x0.y;
            af[2] = (_Float16)x0.z; af[3] = (_Float16)x0.w;
            af[4] = (_Float16)x1.x; af[5] = (_Float16)x1.y;
            af[6] = (_Float16)x1.z; af[7] = (_Float16)x1.w;
#pragma unroll
            for (int nt = 0; nt < 4; ++nt)
                acc[mt][nt] = __builtin_amdgcn_mfma_f32_16x16x32_f16(af, bf[s][nt], acc[mt][nt], 0, 0, 0);
        }
    }

#pragma unroll
    for (int mt = 0; mt < 2; ++mt) {
#pragma unroll
        for (int r4 = 0; r4 < 4; ++r4) {
            int lrow = mh * 32 + mt * 16 + g * 4 + r4;
            int grow = row0 + lrow;
            if (grow > N - 1) grow = N - 1;
            float dv = dinv[grow];
#pragma unroll
            for (int nt = 0; nt < 4; ++nt)
                outs[lrow][nh * 64 + nt * 16 + t] = (_Float16)(acc[mt][nt][r4] * dv);
        }
    }
    __syncthreads();
    {
        int lrow = tid >> 2, c0 = (tid & 3) * 32;
        int grow = row0 + lrow;
        if (grow < N) {
            const half8v* srcp = (const half8v*)&outs[lrow][c0];
            half8v* dstp = (half8v*)(H + (size_t)grow * 128 + c0);
#pragma unroll
            for (int i = 0; i < 4; ++i) dstp[i] = srcp[i];
        }
    }
}

// fdot2 micro-step: a-pair P (literal), 4 output cols from one W2p half8v
#define FDOT_STEP(P)                                                            \
    {                                                                           \
        half8v wv = *(const half8v*)(wbase + (kq * 4 + P) * 128);               \
        half2v ap = __builtin_shufflevector(av, av, 2 * P, 2 * P + 1);          \
        half2v w0 = __builtin_shufflevector(wv, wv, 0, 1);                      \
        half2v w1 = __builtin_shufflevector(wv, wv, 2, 3);                      \
        half2v w2 = __builtin_shufflevector(wv, wv, 4, 5);                      \
        half2v w3 = __builtin_shufflevector(wv, wv, 6, 7);                      \
        o0 = __builtin_amdgcn_fdot2(ap, w0, o0, false);                         \
        o1 = __builtin_amdgcn_fdot2(ap, w1, o1, false);                         \
        o2 = __builtin_amdgcn_fdot2(ap, w2, o2, false);                         \
        o3 = __builtin_amdgcn_fdot2(ap, w3, o3, false);                         \
    }

// Fused: a1[n] = relu(b1 + dinv[n]*(h1w[n] + sum_s h1w[s]))  (16 lanes/node)
//        h2w[n] = dinv[n] * (a1[n] @ W2)   (fdot2, k-pair-interleaved W2 in LDS)
// Nodes taken in degree-sorted perm order: 4 nodes/wave have ~equal degree.
__global__ __launch_bounds__(512) void agg_gemm_kernel(
        const unsigned int* __restrict__ perm, const unsigned short* __restrict__ bucket,
        const float* __restrict__ dinv,
        const _Float16* __restrict__ H1h, const float* __restrict__ b1,
        const float* __restrict__ W2, _Float16* __restrict__ H2h, int nNodes)
{
    __shared__ _Float16 W2p[128 * 64];    // 16 KB
    __shared__ _Float16 a1s[32][136];     // 8.5 KB
    const int tid = threadIdx.x;

    {   // cooperative W2 load + fp16 convert + pair-interleave store
        const float4* Wg = (const float4*)W2;
#pragma unroll
        for (int i = 0; i < 4; ++i) {
            int idx = tid + i * 512;
            float4 fv = Wg[idx];
            int k = idx >> 4, c0 = (idx & 15) * 4;
            _Float16* base = &W2p[(k >> 1) * 128 + (k & 1)];
            base[(c0 + 0) * 2] = (_Float16)fv.x;
            base[(c0 + 1) * 2] = (_Float16)fv.y;
            base[(c0 + 2) * 2] = (_Float16)fv.z;
            base[(c0 + 3) * 2] = (_Float16)fv.w;
        }
    }
    __syncthreads();

    const int w = tid >> 6, lane = tid & 63;
    const int q = lane >> 4, u = lane & 15;   // 4 nodes/wave, 16 lanes/node
    const int nloc = w * 4 + q;
    const int n0 = blockIdx.x * 32 + nloc;

    float a0 = 0.f, a1_ = 0.f, a2 = 0.f, a3 = 0.f, a4 = 0.f, a5 = 0.f, a6 = 0.f, a7 = 0.f;
    float dn = 0.f;
    int nid = 0;
    if (n0 < nNodes) {
        unsigned int pv = perm[n0];
        nid = (int)(pv & 0xFFFFu);
        int c = (int)(pv >> 16);
        dn = dinv[nid];
        const _Float16* Hl = H1h + u * 8;
        half8v sv = *(const half8v*)(Hl + (size_t)nid * 128);
        a0 = (float)sv[0]; a1_ = (float)sv[1]; a2 = (float)sv[2]; a3 = (float)sv[3];
        a4 = (float)sv[4]; a5 = (float)sv[5]; a6 = (float)sv[6]; a7 = (float)sv[7];
        int i = nid * CAP, e0 = i + c;
        for (; i + 8 <= e0; i += 8) {
            ushort8v ix = *(const ushort8v*)(bucket + i);
            half8v v0 = *(const half8v*)(Hl + (size_t)ix[0] * 128);
            half8v v1 = *(const half8v*)(Hl + (size_t)ix[1] * 128);
            half8v v2 = *(const half8v*)(Hl + (size_t)ix[2] * 128);
            half8v v3 = *(const half8v*)(Hl + (size_t)ix[3] * 128);
            half8v v4 = *(const half8v*)(Hl + (size_t)ix[4] * 128);
            half8v v5 = *(const half8v*)(Hl + (size_t)ix[5] * 128);
            half8v v6 = *(const half8v*)(Hl + (size_t)ix[6] * 128);
            half8v v7 = *(const half8v*)(Hl + (size_t)ix[7] * 128);
            half8v t = ((v0 + v1) + (v2 + v3)) + ((v4 + v5) + (v6 + v7));
            a0 += (float)t[0]; a1_ += (float)t[1]; a2 += (float)t[2]; a3 += (float)t[3];
            a4 += (float)t[4]; a5 += (float)t[5]; a6 += (float)t[6]; a7 += (float)t[7];
        }
        for (; i + 4 <= e0; i += 4) {
            ushort4v ix = *(const ushort4v*)(bucket + i);
            half8v va = *(const half8v*)(Hl + (size_t)ix[0] * 128);
            half8v vb = *(const half8v*)(Hl + (size_t)ix[1] * 128);
            half8v vc = *(const half8v*)(Hl + (size_t)ix[2] * 128);
            half8v vd = *(const half8v*)(Hl + (size_t)ix[3] * 128);
            half8v t = (va + vb) + (vc + vd);
            a0 += (float)t[0]; a1_ += (float)t[1]; a2 += (float)t[2]; a3 += (float)t[3];
            a4 += (float)t[4]; a5 += (float)t[5]; a6 += (float)t[6]; a7 += (float)t[7];
        }
        for (; i < e0; ++i) {
            int s = bucket[i];
            half8v v = *(const half8v*)(Hl + (size_t)s * 128);
            a0 += (float)v[0]; a1_ += (float)v[1]; a2 += (float)v[2]; a3 += (float)v[3];
            a4 += (float)v[4]; a5 += (float)v[5]; a6 += (float)v[6]; a7 += (float)v[7];
        }
        float4 b0 = *(const float4*)(b1 + u * 8);
        float4 b4 = *(const float4*)(b1 + u * 8 + 4);
        a0 = fmaxf(b0.x + dn * a0, 0.f); a1_ = fmaxf(b0.y + dn * a1_, 0.f);
        a2 = fmaxf(b0.z + dn * a2, 0.f); a3 = fmaxf(b0.w + dn * a3, 0.f);
        a4 = fmaxf(b4.x + dn * a4, 0.f); a5 = fmaxf(b4.y + dn * a5, 0.f);
        a6 = fmaxf(b4.z + dn * a6, 0.f); a7 = fmaxf(b4.w + dn * a7, 0.f);
    }
    {
        half8v ah;
        ah[0] = (_Float16)a0; ah[1] = (_Float16)a1_; ah[2] = (_Float16)a2; ah[3] = (_Float16)a3;
        ah[4] = (_Float16)a4; ah[5] = (_Float16)a5; ah[6] = (_Float16)a6; ah[7] = (_Float16)a7;
        *(half8v*)&a1s[nloc][u * 8] = ah;
    }
    asm volatile("s_waitcnt lgkmcnt(0)" ::: "memory");

    {
        float o0 = 0.f, o1 = 0.f, o2 = 0.f, o3 = 0.f;
        const _Float16* arow = &a1s[nloc][0];
        const _Float16* wbase = &W2p[u * 8];
#pragma unroll 4
        for (int kq = 0; kq < 16; ++kq) {
            half8v av = *(const half8v*)(arow + kq * 8);
            FDOT_STEP(0)
            FDOT_STEP(1)
            FDOT_STEP(2)
            FDOT_STEP(3)
        }
        if (n0 < nNodes) {
            half4v o;
            o[0] = (_Float16)(dn * o0); o[1] = (_Float16)(dn * o1);
            o[2] = (_Float16)(dn * o2); o[3] = (_Float16)(dn * o3);
            *(half4v*)(H2h + (size_t)nid * 64 + u * 4) = o;
        }
    }
}

// out[n] = b2 + dinv[n]*( h2w[n] + sum_s h2w[s] ), 8 lanes/node, perm order
__global__ __launch_bounds__(256) void agg2_kernel(
        const unsigned int* __restrict__ perm, const unsigned short* __restrict__ bucket,
        const float* __restrict__ dinv,
        const _Float16* __restrict__ Hh, const float* __restrict__ bias,
        float* __restrict__ Out, int nNodes)
{
    const int tid = threadIdx.x;
    const int w = tid >> 6, lane = tid & 63;
    const int q = lane >> 3, u = lane & 7;    // 8 nodes/wave, 8 lanes/node
    const int n0 = blockIdx.x * 32 + w * 8 + q;
    if (n0 >= nNodes) return;
    unsigned int pv = perm[n0];
    const int n = (int)(pv & 0xFFFFu);
    int c = (int)(pv >> 16);
    float dn = dinv[n];
    const _Float16* Hl = Hh + u * 8;
    half8v sv = *(const half8v*)(Hl + (size_t)n * 64);
    float a0 = (float)sv[0], a1_ = (float)sv[1], a2 = (float)sv[2], a3 = (float)sv[3];
    float a4 = (float)sv[4], a5 = (float)sv[5], a6 = (float)sv[6], a7 = (float)sv[7];
    int i = n * CAP, e0 = i + c;
    for (; i + 8 <= e0; i += 8) {
        ushort8v ix = *(const ushort8v*)(bucket + i);
        half8v v0 = *(const half8v*)(Hl + (size_t)ix[0] * 64);
        half8v v1 = *(const half8v*)(Hl + (size_t)ix[1] * 64);
        half8v v2 = *(const half8v*)(Hl + (size_t)ix[2] * 64);
        half8v v3 = *(const half8v*)(Hl + (size_t)ix[3] * 64);
        half8v v4 = *(const half8v*)(Hl + (size_t)ix[4] * 64);
        half8v v5 = *(const half8v*)(Hl + (size_t)ix[5] * 64);
        half8v v6 = *(const half8v*)(Hl + (size_t)ix[6] * 64);
        half8v v7 = *(const half8v*)(Hl + (size_t)ix[7] * 64);
        half8v t = ((v0 + v1) + (v2 + v3)) + ((v4 + v5) + (v6 + v7));
        a0 += (float)t[0]; a1_ += (float)t[1]; a2 += (float)t[2]; a3 += (float)t[3];
        a4 += (float)t[4]; a5 += (float)t[5]; a6 += (float)t[6]; a7 += (float)t[7];
    }
    for (; i + 4 <= e0; i += 4) {
        ushort4v ix = *(const ushort4v*)(bucket + i);
        half8v va = *(const half8v*)(Hl + (size_t)ix[0] * 64);
        half8v vb = *(const half8v*)(Hl + (size_t)ix[1] * 64);
        half8v vc = *(const half8v*)(Hl + (size_t)ix[2] * 64);
        half8v vd = *(const half8v*)(Hl + (size_t)ix[3] * 64);
        half8v t = (va + vb) + (vc + vd);
        a0 += (float)t[0]; a1_ += (float)t[1]; a2 += (float)t[2]; a3 += (float)t[3];
        a4 += (float)t[4]; a5 += (float)t[5]; a6 += (float)t[6]; a7 += (float)t[7];
    }
    for (; i < e0; ++i) {
        int s = bucket[i];
        half8v v = *(const half8v*)(Hl + (size_t)s * 64);
        a0 += (float)v[0]; a1_ += (float)v[1]; a2 += (float)v[2]; a3 += (float)v[3];
        a4 += (float)v[4]; a5 += (float)v[5]; a6 += (float)v[6]; a7 += (float)v[7];
    }
    float4 b0 = *(const float4*)(bias + u * 8);
    float4 b4 = *(const float4*)(bias + u * 8 + 4);
    float* op = Out + (size_t)n * 64 + u * 8;
    *(float4*)op       = make_float4(b0.x + dn * a0, b0.y + dn * a1_, b0.z + dn * a2, b0.w + dn * a3);
    *(float4*)(op + 4) = make_float4(b4.x + dn * a4, b4.y + dn * a5, b4.z + dn * a6, b4.w + dn * a7);
}

extern "C" void kernel_launch(void* const* d_in, const int* in_sizes, int n_in,
                              void* d_out, int out_size, void* d_ws, size_t ws_size,
                              hipStream_t stream) {
    const float* x  = (const float*)d_in[0];
    const int*   ei = (const int*)d_in[1];
    const float* W1 = (const float*)d_in[2];
    const float* b1 = (const float*)d_in[3];
    const float* W2 = (const float*)d_in[4];
    const float* b2 = (const float*)d_in[5];
    float* out = (float*)d_out;
    char* wsb  = (char*)d_ws;

    const int* srcA = ei;
    const int* dstA = ei + NEDGES;

    _Float16* h1h = (_Float16*)wsb;                        // 50000*128 fp16
    _Float16* h2h = h1h + (size_t)NNODES * 128;            // 50000*64 fp16
    unsigned short* bucket = (unsigned short*)(h2h + (size_t)NNODES * 64); // 50000*64 ushort
    int*   pcnt   = (int*)(bucket + (size_t)NNODES * CAP); // 196
    float* dinv   = (float*)(pcnt + NPF);                  // 50000
    unsigned int* perm = (unsigned int*)(dinv + NNODES);   // 50000
    unsigned int* binned = (unsigned int*)(perm + NNODES); // 196*8192*4B = 6.4 MB

    zero_pcnt<<<1, 256, 0, stream>>>(pcnt);
    bin_kernel<<<NBINBLK, 256, 0, stream>>>(srcA, dstA, pcnt, binned);
    fillB_kernel<<<NPF, 512, 0, stream>>>(binned, pcnt, dinv, perm, bucket);

    gemm1_mfma<<<(NNODES + 63) / 64, 256, 0, stream>>>(x, W1, dinv, h1h, NNODES);
    agg_gemm_kernel<<<(NNODES + 31) / 32, 512, 0, stream>>>(perm, bucket, dinv, h1h, b1, W2, h2h, NNODES);
    agg2_kernel<<<(NNODES + 31) / 32, 256, 0, stream>>>(perm, bucket, dinv, h2h, b2, out, NNODES);
}

// Round 16
// 94.237 us; speedup vs baseline: 1.1702x; 1.1702x over previous
//
#include <hip/hip_runtime.h>

#define NNODES 50000
#define NEDGES 800000
#define CAP 64                         // bucket capacity per node (max deg ~45 for Poisson(16))
#define PFINE 256                      // nodes per fine partition
#define NPF ((NNODES + PFINE - 1) / PFINE)   // 196
#define CAPPF 8192                     // binned capacity per partition
#define EPB 4096                       // edges per bin block (fewer blocks -> 4x fewer pcnt atomics)
#define NBINBLK ((NEDGES + EPB - 1) / EPB)   // 196

typedef _Float16 half2v __attribute__((ext_vector_type(2)));
typedef _Float16 half4v __attribute__((ext_vector_type(4)));
typedef _Float16 half8v __attribute__((ext_vector_type(8)));
typedef float floatx4 __attribute__((ext_vector_type(4)));
typedef unsigned short ushort4v __attribute__((ext_vector_type(4)));
typedef unsigned short ushort8v __attribute__((ext_vector_type(8)));

__global__ void zero_pcnt(int* __restrict__ p) {
    if (threadIdx.x < NPF) p[threadIdx.x] = 0;
}

// Phase A: bin edges by fine partition (d>>8). Packed: (src<<8) | (d&255).
__global__ __launch_bounds__(512) void bin_kernel(
        const int* __restrict__ src, const int* __restrict__ dst,
        int* __restrict__ pcnt, unsigned int* __restrict__ binned) {
    __shared__ int lcnt[NPF];
    __shared__ int gbase[NPF];
    const int tid = threadIdx.x;
    for (int i = tid; i < NPF; i += 512) lcnt[i] = 0;
    __syncthreads();
    const int e0 = blockIdx.x * EPB;
    int myp[8], myrank[8];
    unsigned int myval[8];
#pragma unroll
    for (int k = 0; k < 8; ++k) {
        int e = e0 + k * 512 + tid;
        if (e < NEDGES) {
            int d = dst[e], s = src[e];
            int p = d >> 8;
            myp[k] = p;
            myrank[k] = atomicAdd(&lcnt[p], 1);
            myval[k] = ((unsigned int)s << 8) | (unsigned int)(d & 255);
        } else myp[k] = -1;
    }
    __syncthreads();
    for (int p = tid; p < NPF; p += 512) gbase[p] = atomicAdd(&pcnt[p], lcnt[p]);
    __syncthreads();
#pragma unroll
    for (int k = 0; k < 8; ++k) {
        if (myp[k] >= 0) {
            int idx = gbase[myp[k]] + myrank[k];
            if (idx < CAPPF) binned[(size_t)myp[k] * CAPPF + idx] = myval[k];
        }
    }
}

// Phase B: build one partition's bucket region in LDS (LDS atomics), stream out
// full lines. cnt + dinv written directly (no global atomics).
__global__ __launch_bounds__(512) void fillB_kernel(
        const unsigned int* __restrict__ binned, const int* __restrict__ pcnt,
        int* __restrict__ cnt, float* __restrict__ dinv,
        unsigned short* __restrict__ bucket) {
    __shared__ __align__(16) unsigned short lbuck[PFINE * CAP];  // 32 KB
    __shared__ int lcnt[PFINE];                                  // 1 KB
    const int tid = threadIdx.x;
    const int p = blockIdx.x;
    for (int i = tid; i < PFINE; i += 512) lcnt[i] = 0;
    __syncthreads();
    int n = pcnt[p]; if (n > CAPPF) n = CAPPF;
    const unsigned int* bp = binned + (size_t)p * CAPPF;
    for (int i = tid; i < n; i += 512) {
        unsigned int v = bp[i];
        int dl = (int)(v & 255u);
        int pos = atomicAdd(&lcnt[dl], 1);
        if (pos < CAP) lbuck[dl * CAP + pos] = (unsigned short)(v >> 8);
    }
    __syncthreads();
    const int nodebase = p * PFINE;
    int nn = NNODES - nodebase; if (nn > PFINE) nn = PFINE;
    int4* gb = (int4*)(bucket + (size_t)nodebase * CAP);
    const int4* lb = (const int4*)lbuck;
    const int tot4 = nn * (CAP / 8);
    for (int i = tid; i < tot4; i += 512) gb[i] = lb[i];
    for (int i = tid; i < nn; i += 512) {
        int c = lcnt[i];
        cnt[nodebase + i] = c;
        dinv[nodebase + i] = 1.0f / sqrtf((float)c + 1.0f);
    }
}

// h1w[r,:] = dinv[r] * (X[r,:] @ W1)  via fp16 MFMA, fp16 output.
__global__ __launch_bounds__(256) void gemm1_mfma(
    const float* __restrict__ X, const float* __restrict__ W,
    const float* __restrict__ dinv, _Float16* __restrict__ H, int N)
{
    __shared__ _Float16 outs[64][136];
    const int tid  = threadIdx.x;
    const int lane = tid & 63;
    const int wv   = tid >> 6;
    const int mh   = wv >> 1;
    const int nh   = wv & 1;
    const int t    = lane & 15;
    const int g    = lane >> 4;
    const int row0 = blockIdx.x * 64;

    half8v bf[4][4];
#pragma unroll
    for (int s = 0; s < 4; ++s) {
#pragma unroll
        for (int nt = 0; nt < 4; ++nt) {
            const float* wp = W + (size_t)(s * 32 + g * 8) * 128 + nh * 64 + nt * 16 + t;
            half8v h;
#pragma unroll
            for (int i = 0; i < 8; ++i) h[i] = (_Float16)wp[(size_t)i * 128];
            bf[s][nt] = h;
        }
    }

    floatx4 acc[2][4];
#pragma unroll
    for (int mt = 0; mt < 2; ++mt)
#pragma unroll
        for (int nt = 0; nt < 4; ++nt) acc[mt][nt] = (floatx4){0.f, 0.f, 0.f, 0.f};

#pragma unroll
    for (int s = 0; s < 4; ++s) {
#pragma unroll
        for (int mt = 0; mt < 2; ++mt) {
            int r = row0 + mh * 32 + mt * 16 + t;
            if (r > N - 1) r = N - 1;
            const float* xp = X + (size_t)r * 128 + s * 32 + g * 8;
            float4 x0 = *(const float4*)xp;
            float4 x1 = *(const float4*)(xp + 4);
            half8v af;
            af[0] = (_Float16)x0.x; af[1] = (_Float16)x0.y;
            af[2] = (_Float16)x0.z; af[3] = (_Float16)x0.w;
            af[4] = (_Float16)x1.x; af[5] = (_Float16)x1.y;
            af[6] = (_Float16)x1.z; af[7] = (_Float16)x1.w;
#pragma unroll
            for (int nt = 0; nt < 4; ++nt)
                acc[mt][nt] = __builtin_amdgcn_mfma_f32_16x16x32_f16(af, bf[s][nt], acc[mt][nt], 0, 0, 0);
        }
    }

#pragma unroll
    for (int mt = 0; mt < 2; ++mt) {
#pragma unroll
        for (int r4 = 0; r4 < 4; ++r4) {
            int lrow = mh * 32 + mt * 16 + g * 4 + r4;
            int grow = row0 + lrow;
            if (grow > N - 1) grow = N - 1;
            float dv = dinv[grow];
#pragma unroll
            for (int nt = 0; nt < 4; ++nt)
                outs[lrow][nh * 64 + nt * 16 + t] = (_Float16)(acc[mt][nt][r4] * dv);
        }
    }
    __syncthreads();
    {
        int lrow = tid >> 2, c0 = (tid & 3) * 32;
        int grow = row0 + lrow;
        if (grow < N) {
            const half8v* srcp = (const half8v*)&outs[lrow][c0];
            half8v* dstp = (half8v*)(H + (size_t)grow * 128 + c0);
#pragma unroll
            for (int i = 0; i < 4; ++i) dstp[i] = srcp[i];
        }
    }
}

// fdot2 micro-step: a-pair P (literal), 4 output cols from one W2p half8v
#define FDOT_STEP(P)                                                            \
    {                                                                           \
        half8v wv = *(const half8v*)(wbase + (kq * 4 + P) * 128);               \
        half2v ap = __builtin_shufflevector(av, av, 2 * P, 2 * P + 1);          \
        half2v w0 = __builtin_shufflevector(wv, wv, 0, 1);                      \
        half2v w1 = __builtin_shufflevector(wv, wv, 2, 3);                      \
        half2v w2 = __builtin_shufflevector(wv, wv, 4, 5);                      \
        half2v w3 = __builtin_shufflevector(wv, wv, 6, 7);                      \
        o0 = __builtin_amdgcn_fdot2(ap, w0, o0, false);                         \
        o1 = __builtin_amdgcn_fdot2(ap, w1, o1, false);                         \
        o2 = __builtin_amdgcn_fdot2(ap, w2, o2, false);                         \
        o3 = __builtin_amdgcn_fdot2(ap, w3, o3, false);                         \
    }

// Fused: a1[n] = relu(b1 + dinv[n]*(h1w[n] + sum_s h1w[s]))  (16 lanes/node, 8-deep gather)
//        h2w[n] = dinv[n] * (a1[n] @ W2)   (fdot2 with k-pair-interleaved W2 in LDS)
__global__ __launch_bounds__(512) void agg_gemm_kernel(
        const int* __restrict__ cnt, const unsigned short* __restrict__ bucket,
        const float* __restrict__ dinv,
        const _Float16* __restrict__ H1h, const float* __restrict__ b1,
        const float* __restrict__ W2, _Float16* __restrict__ H2h, int nNodes)
{
    __shared__ _Float16 W2p[128 * 64];    // 16 KB, [kp][c][parity]
    __shared__ _Float16 a1s[32][136];     // 8.5 KB fp16, padded rows
    const int tid = threadIdx.x;

    {   // cooperative W2 load + fp16 convert + pair-interleave store
        const float4* Wg = (const float4*)W2;
#pragma unroll
        for (int i = 0; i < 4; ++i) {
            int idx = tid + i * 512;
            float4 fv = Wg[idx];
            int k = idx >> 4, c0 = (idx & 15) * 4;
            _Float16* base = &W2p[(k >> 1) * 128 + (k & 1)];
            base[(c0 + 0) * 2] = (_Float16)fv.x;
            base[(c0 + 1) * 2] = (_Float16)fv.y;
            base[(c0 + 2) * 2] = (_Float16)fv.z;
            base[(c0 + 3) * 2] = (_Float16)fv.w;
        }
    }
    __syncthreads();

    const int w = tid >> 6, lane = tid & 63;
    const int q = lane >> 4, u = lane & 15;   // 4 nodes/wave, 16 lanes/node
    const int nloc = w * 4 + q;
    const int nid = blockIdx.x * 32 + nloc;

    float a0 = 0.f, a1_ = 0.f, a2 = 0.f, a3 = 0.f, a4 = 0.f, a5 = 0.f, a6 = 0.f, a7 = 0.f;
    float dn = 0.f;
    if (nid < nNodes) {
        dn = dinv[nid];
        const _Float16* Hl = H1h + u * 8;
        half8v sv = *(const half8v*)(Hl + (size_t)nid * 128);
        a0 = (float)sv[0]; a1_ = (float)sv[1]; a2 = (float)sv[2]; a3 = (float)sv[3];
        a4 = (float)sv[4]; a5 = (float)sv[5]; a6 = (float)sv[6]; a7 = (float)sv[7];
        int c = cnt[nid]; if (c > CAP) c = CAP;
        int i = nid * CAP, e0 = i + c;
        for (; i + 8 <= e0; i += 8) {
            ushort8v ix = *(const ushort8v*)(bucket + i);
            half8v v0 = *(const half8v*)(Hl + (size_t)ix[0] * 128);
            half8v v1 = *(const half8v*)(Hl + (size_t)ix[1] * 128);
            half8v v2 = *(const half8v*)(Hl + (size_t)ix[2] * 128);
            half8v v3 = *(const half8v*)(Hl + (size_t)ix[3] * 128);
            half8v v4 = *(const half8v*)(Hl + (size_t)ix[4] * 128);
            half8v v5 = *(const half8v*)(Hl + (size_t)ix[5] * 128);
            half8v v6 = *(const half8v*)(Hl + (size_t)ix[6] * 128);
            half8v v7 = *(const half8v*)(Hl + (size_t)ix[7] * 128);
            half8v t = ((v0 + v1) + (v2 + v3)) + ((v4 + v5) + (v6 + v7));
            a0 += (float)t[0]; a1_ += (float)t[1]; a2 += (float)t[2]; a3 += (float)t[3];
            a4 += (float)t[4]; a5 += (float)t[5]; a6 += (float)t[6]; a7 += (float)t[7];
        }
        for (; i + 4 <= e0; i += 4) {
            ushort4v ix = *(const ushort4v*)(bucket + i);
            half8v va = *(const half8v*)(Hl + (size_t)ix[0] * 128);
            half8v vb = *(const half8v*)(Hl + (size_t)ix[1] * 128);
            half8v vc = *(const half8v*)(Hl + (size_t)ix[2] * 128);
            half8v vd = *(const half8v*)(Hl + (size_t)ix[3] * 128);
            half8v t = (va + vb) + (vc + vd);
            a0 += (float)t[0]; a1_ += (float)t[1]; a2 += (float)t[2]; a3 += (float)t[3];
            a4 += (float)t[4]; a5 += (float)t[5]; a6 += (float)t[6]; a7 += (float)t[7];
        }
        for (; i < e0; ++i) {
            int s = bucket[i];
            half8v v = *(const half8v*)(Hl + (size_t)s * 128);
            a0 += (float)v[0]; a1_ += (float)v[1]; a2 += (float)v[2]; a3 += (float)v[3];
            a4 += (float)v[4]; a5 += (float)v[5]; a6 += (float)v[6]; a7 += (float)v[7];
        }
        float4 b0 = *(const float4*)(b1 + u * 8);
        float4 b4 = *(const float4*)(b1 + u * 8 + 4);
        a0 = fmaxf(b0.x + dn * a0, 0.f); a1_ = fmaxf(b0.y + dn * a1_, 0.f);
        a2 = fmaxf(b0.z + dn * a2, 0.f); a3 = fmaxf(b0.w + dn * a3, 0.f);
        a4 = fmaxf(b4.x + dn * a4, 0.f); a5 = fmaxf(b4.y + dn * a5, 0.f);
        a6 = fmaxf(b4.z + dn * a6, 0.f); a7 = fmaxf(b4.w + dn * a7, 0.f);
    }
    {
        half8v ah;
        ah[0] = (_Float16)a0; ah[1] = (_Float16)a1_; ah[2] = (_Float16)a2; ah[3] = (_Float16)a3;
        ah[4] = (_Float16)a4; ah[5] = (_Float16)a5; ah[6] = (_Float16)a6; ah[7] = (_Float16)a7;
        *(half8v*)&a1s[nloc][u * 8] = ah;
    }
    asm volatile("s_waitcnt lgkmcnt(0)" ::: "memory");

    {
        float o0 = 0.f, o1 = 0.f, o2 = 0.f, o3 = 0.f;
        const _Float16* arow = &a1s[nloc][0];
        const _Float16* wbase = &W2p[u * 8];
#pragma unroll 4
        for (int kq = 0; kq < 16; ++kq) {
            half8v av = *(const half8v*)(arow + kq * 8);
            FDOT_STEP(0)
            FDOT_STEP(1)
            FDOT_STEP(2)
            FDOT_STEP(3)
        }
        if (nid < nNodes) {
            half4v o;
            o[0] = (_Float16)(dn * o0); o[1] = (_Float16)(dn * o1);
            o[2] = (_Float16)(dn * o2); o[3] = (_Float16)(dn * o3);
            *(half4v*)(H2h + (size_t)nid * 64 + u * 4) = o;
        }
    }
}

// out[n] = b2 + dinv[n]*( h2w[n] + sum_s h2w[s] ), 8 lanes/node, 8-deep fp16 tree
__global__ __launch_bounds__(256) void agg2_kernel(
        const int* __restrict__ cnt, const unsigned short* __restrict__ bucket,
        const float* __restrict__ dinv,
        const _Float16* __restrict__ Hh, const float* __restrict__ bias,
        float* __restrict__ Out, int nNodes)
{
    const int tid = threadIdx.x;
    const int w = tid >> 6, lane = tid & 63;
    const int q = lane >> 3, u = lane & 7;    // 8 nodes/wave, 8 lanes/node
    const int n = blockIdx.x * 32 + w * 8 + q;
    if (n >= nNodes) return;
    float dn = dinv[n];
    const _Float16* Hl = Hh + u * 8;
    half8v sv = *(const half8v*)(Hl + (size_t)n * 64);
    float a0 = (float)sv[0], a1_ = (float)sv[1], a2 = (float)sv[2], a3 = (float)sv[3];
    float a4 = (float)sv[4], a5 = (float)sv[5], a6 = (float)sv[6], a7 = (float)sv[7];
    int c = cnt[n]; if (c > CAP) c = CAP;
    int i = n * CAP, e0 = i + c;
    for (; i + 8 <= e0; i += 8) {
        ushort8v ix = *(const ushort8v*)(bucket + i);
        half8v v0 = *(const half8v*)(Hl + (size_t)ix[0] * 64);
        half8v v1 = *(const half8v*)(Hl + (size_t)ix[1] * 64);
        half8v v2 = *(const half8v*)(Hl + (size_t)ix[2] * 64);
        half8v v3 = *(const half8v*)(Hl + (size_t)ix[3] * 64);
        half8v v4 = *(const half8v*)(Hl + (size_t)ix[4] * 64);
        half8v v5 = *(const half8v*)(Hl + (size_t)ix[5] * 64);
        half8v v6 = *(const half8v*)(Hl + (size_t)ix[6] * 64);
        half8v v7 = *(const half8v*)(Hl + (size_t)ix[7] * 64);
        half8v t = ((v0 + v1) + (v2 + v3)) + ((v4 + v5) + (v6 + v7));
        a0 += (float)t[0]; a1_ += (float)t[1]; a2 += (float)t[2]; a3 += (float)t[3];
        a4 += (float)t[4]; a5 += (float)t[5]; a6 += (float)t[6]; a7 += (float)t[7];
    }
    for (; i + 4 <= e0; i += 4) {
        ushort4v ix = *(const ushort4v*)(bucket + i);
        half8v va = *(const half8v*)(Hl + (size_t)ix[0] * 64);
        half8v vb = *(const half8v*)(Hl + (size_t)ix[1] * 64);
        half8v vc = *(const half8v*)(Hl + (size_t)ix[2] * 64);
        half8v vd = *(const half8v*)(Hl + (size_t)ix[3] * 64);
        half8v t = (va + vb) + (vc + vd);
        a0 += (float)t[0]; a1_ += (float)t[1]; a2 += (float)t[2]; a3 += (float)t[3];
        a4 += (float)t[4]; a5 += (float)t[5]; a6 += (float)t[6]; a7 += (float)t[7];
    }
    for (; i < e0; ++i) {
        int s = bucket[i];
        half8v v = *(const half8v*)(Hl + (size_t)s * 64);
        a0 += (float)v[0]; a1_ += (float)v[1]; a2 += (float)v[2]; a3 += (float)v[3];
        a4 += (float)v[4]; a5 += (float)v[5]; a6 += (float)v[6]; a7 += (float)v[7];
    }
    float4 b0 = *(const float4*)(bias + u * 8);
    float4 b4 = *(const float4*)(bias + u * 8 + 4);
    float* op = Out + (size_t)n * 64 + u * 8;
    *(float4*)op       = make_float4(b0.x + dn * a0, b0.y + dn * a1_, b0.z + dn * a2, b0.w + dn * a3);
    *(float4*)(op + 4) = make_float4(b4.x + dn * a4, b4.y + dn * a5, b4.z + dn * a6, b4.w + dn * a7);
}

extern "C" void kernel_launch(void* const* d_in, const int* in_sizes, int n_in,
                              void* d_out, int out_size, void* d_ws, size_t ws_size,
                              hipStream_t stream) {
    const float* x  = (const float*)d_in[0];
    const int*   ei = (const int*)d_in[1];
    const float* W1 = (const float*)d_in[2];
    const float* b1 = (const float*)d_in[3];
    const float* W2 = (const float*)d_in[4];
    const float* b2 = (const float*)d_in[5];
    float* out = (float*)d_out;
    char* wsb  = (char*)d_ws;

    const int* srcA = ei;
    const int* dstA = ei + NEDGES;

    _Float16* h1h = (_Float16*)wsb;                        // 50000*128 fp16
    _Float16* h2h = h1h + (size_t)NNODES * 128;            // 50000*64 fp16
    unsigned short* bucket = (unsigned short*)(h2h + (size_t)NNODES * 64); // 50000*64 ushort
    int*   cnt    = (int*)(bucket + (size_t)NNODES * CAP); // 50000
    int*   pcnt   = cnt + NNODES;                          // 196
    float* dinv   = (float*)(pcnt + NPF);                  // 50000
    unsigned int* binned = (unsigned int*)(dinv + NNODES); // 196*8192*4B = 6.4 MB

    zero_pcnt<<<1, 256, 0, stream>>>(pcnt);
    bin_kernel<<<NBINBLK, 512, 0, stream>>>(srcA, dstA, pcnt, binned);
    fillB_kernel<<<NPF, 512, 0, stream>>>(binned, pcnt, cnt, dinv, bucket);

    gemm1_mfma<<<(NNODES + 63) / 64, 256, 0, stream>>>(x, W1, dinv, h1h, NNODES);
    agg_gemm_kernel<<<(NNODES + 31) / 32, 512, 0, stream>>>(cnt, bucket, dinv, h1h, b1, W2, h2h, NNODES);
    agg2_kernel<<<(NNODES + 31) / 32, 256, 0, stream>>>(cnt, bucket, dinv, h2h, b2, out, NNODES);
}